// Round 1
// baseline (6068.132 us; speedup 1.0000x reference)
//
#include <hip/hip_runtime.h>
#include <hip/hip_cooperative_groups.h>

namespace cg = cooperative_groups;

#define T_STEPS 32
#define BATCH   16
#define IN_DIM  64
#define OUT_DIM 64
#define L_MEM   4096
#define W_DIM   64
#define NIN     192   // IN+OUT+W
#define CO      332   // OUT + 70 + 198
#define CPB     16    // blocks (L-chunks) per batch
#define LB      256   // L_MEM / CPB
#define NBLK    256   // BATCH * CPB
#define NTHR    256
#define N_EXTRA 202
#define EX_PER_BLK 13

__device__ __forceinline__ float waveSum(float v) {
#pragma unroll
  for (int off = 32; off > 0; off >>= 1) v += __shfl_xor(v, off, 64);
  return v;
}
__device__ __forceinline__ float sigmoidf(float x) { return 1.f / (1.f + __expf(-x)); }
__device__ __forceinline__ float softplusf(float x) { return x > 15.f ? x : log1pf(__expf(x)); }

// extra (non-redundant) controller columns: out[0:64], g_r/gam_r/s_r (129..133),
// g_w/gam_w/s_w (199..203), e (204..267), a (268..331)
__device__ __forceinline__ int extra_col(int i) {
  if (i < 64) return i;
  if (i < 69) return 129 + (i - 64);
  if (i < 74) return 199 + (i - 69);
  return 204 + (i - 74);
}

__global__ void __launch_bounds__(NTHR, 1) ntm_kernel(
    const float* __restrict__ inp, const float* __restrict__ Wc,
    const float* __restrict__ bcv, float* __restrict__ dout,
    float* __restrict__ memT, float* __restrict__ erR, float* __restrict__ erW,
    float* __restrict__ wbR, float* __restrict__ wbW,
    float* __restrict__ wpR, float* __restrict__ wpW,
    float* __restrict__ outbuf, float* __restrict__ Rbuf,
    float* __restrict__ Sbuf, float* __restrict__ praw)
{
  cg::grid_group grid = cg::this_grid();
  const int blk   = blockIdx.x;
  const int b     = blk >> 4;     // batch
  const int chunk = blk & 15;     // L-chunk
  const int tid   = threadIdx.x;
  const int wave  = tid >> 6;
  const int lane  = tid & 63;
  const int l0    = chunk * LB;

  __shared__ float xin[NIN];
  __shared__ float kr[W_DIM], kw[W_DIM];
  __shared__ float sc[4];               // invnk_r, beta_r, invnk_w, beta_w
  __shared__ float rpart[W_DIM];
  __shared__ float elds[W_DIM], alds[W_DIM];

  float* mT = memT + (size_t)b * W_DIM * L_MEM;  // memT[b][w][l]

  // ---------------- prologue: init poisoned workspace ----------------
  for (int w = wave; w < W_DIM; w += 4) {
    float* p = mT + (size_t)w * L_MEM + l0;
    for (int i = lane; i < LB; i += 64) p[i] = 0.f;
  }
  for (int i = tid; i < LB; i += NTHR) {
    wpR[b * L_MEM + l0 + i] = 0.f;
    wpW[b * L_MEM + l0 + i] = 0.f;
  }
  if (chunk == 0) {
    if (tid < W_DIM) Rbuf[b * W_DIM + tid] = 0.f;
    if (tid < OUT_DIM) {
      outbuf[b * OUT_DIM + tid] = 0.f;
      outbuf[(BATCH + b) * OUT_DIM + tid] = 0.f;
    }
    if (tid == 0) {
      wpR[b * L_MEM] = 1.f;   // w0 = one-hot at l=0 (tid0 zeroed idx0 above)
      wpW[b * L_MEM] = 1.f;
      Sbuf[b] = 0.f; Sbuf[16 + b] = 0.f; Sbuf[32 + b] = 0.f; Sbuf[48 + b] = 0.f;
    }
  }
  __threadfence();
  grid.sync();

  for (int t = 0; t < T_STEPS; ++t) {
    // ---------------- phase 1: controller columns ----------------
    {
      const float* xb = inp + ((size_t)t * BATCH + b) * IN_DIM;
      const float* ob = outbuf + ((t & 1) * BATCH + b) * OUT_DIM;
      if (tid < IN_DIM)                xin[tid] = xb[tid];
      else if (tid < IN_DIM + OUT_DIM) xin[tid] = ob[tid - IN_DIM];
      else if (tid < NIN)              xin[tid] = Rbuf[b * W_DIM + (tid - IN_DIM - OUT_DIM)];
      __syncthreads();

      int col = -1, eidx = -1;
      if (tid < 65)       col = 64 + tid;          // k_r (64..127) + beta_r (128)
      else if (tid < 130) col = 134 + (tid - 65);  // k_w (134..197) + beta_w (198)
      else if (tid < 130 + EX_PER_BLK) {
        int e = chunk * EX_PER_BLK + (tid - 130);
        if (e < N_EXTRA) { eidx = e; col = extra_col(e); }
      }
      float acc = 0.f;
      if (col >= 0) {
        acc = bcv[col];
        const float* wc = Wc + col;
#pragma unroll 8
        for (int i = 0; i < NIN; ++i) acc = fmaf(xin[i], wc[(size_t)i * CO], acc);
      }
      if (tid < 64)        kr[tid] = acc;
      else if (tid == 64)  sc[1] = softplusf(acc);
      else if (tid < 129)  kw[tid - 65] = acc;
      else if (tid == 129) sc[3] = softplusf(acc);
      else if (eidx >= 0) {
        praw[b * CO + col] = acc;
        if (col < OUT_DIM) {
          dout[((size_t)t * BATCH + b) * OUT_DIM + col] = acc;
          outbuf[(((t + 1) & 1) * BATCH + b) * OUT_DIM + col] = acc;
        }
      }
      __syncthreads();
      if (wave == 0) {
        float v = kr[lane];
        float ss = waveSum(v * v);
        if (lane == 0) sc[0] = 1.f / sqrtf(ss + 1e-14f);
      } else if (wave == 1) {
        float v = kw[lane];
        float ss = waveSum(v * v);
        if (lane == 0) sc[2] = 1.f / sqrtf(ss + 1e-14f);
      }
      __syncthreads();
    }

    // ---------------- phase 2: content addressing over own L-chunk ----------------
    {
      const float invnkR = sc[0], betaR = sc[1], invnkW = sc[2], betaW = sc[3];
      const int l = l0 + wave * 64 + lane;       // one l per lane
      const float* mp = mT + l;
      float ss = 0.f, dr = 0.f, dw = 0.f;
#pragma unroll 8
      for (int w = 0; w < W_DIM; ++w) {
        float v = mp[(size_t)w * L_MEM];
        ss = fmaf(v, v, ss);
        dr = fmaf(v, kr[w], dr);
        dw = fmaf(v, kw[w], dw);
      }
      float rinv = rsqrtf(ss + 1e-14f);
      float Kr = dr * rinv * invnkR;
      float Kw = dw * rinv * invnkW;
      // exp(beta*(K-1)) == softmax numerator shifted by -beta: K<=1 -> always stable
      float eRv = __expf(betaR * (Kr - 1.f));
      float eWv = __expf(betaW * (Kw - 1.f));
      erR[b * L_MEM + l] = eRv;
      erW[b * L_MEM + l] = eWv;
      float s1 = waveSum(eRv);
      float s2 = waveSum(eWv);
      if (lane == 0) { atomicAdd(&Sbuf[b], s1); atomicAdd(&Sbuf[16 + b], s2); }
      if (chunk == 0 && tid == 0) { Sbuf[32 + b] = 0.f; Sbuf[48 + b] = 0.f; }  // zero P
    }
    __threadfence();
    grid.sync();   // sync a

    // ---------------- phase 3: gate + shift + sharpen ----------------
    {
      const float invSR = 1.f / Sbuf[b], invSW = 1.f / Sbuf[16 + b];
      const float* pb = praw + b * CO;
      float gR  = sigmoidf(pb[129]);
      float gaR = softplusf(pb[130]) + 1.f;
      float x0 = pb[131], x1 = pb[132], x2 = pb[133];
      float m  = fmaxf(x0, fmaxf(x1, x2));
      float e0 = __expf(x0 - m), e1 = __expf(x1 - m), e2 = __expf(x2 - m);
      float es = 1.f / (e0 + e1 + e2);
      float sr0 = e0 * es, sr1 = e1 * es, sr2 = e2 * es;
      float gW  = sigmoidf(pb[199]);
      float gaW = softplusf(pb[200]) + 1.f;
      float y0 = pb[201], y1 = pb[202], y2 = pb[203];
      float mw = fmaxf(y0, fmaxf(y1, y2));
      float f0 = __expf(y0 - mw), f1 = __expf(y1 - mw), f2 = __expf(y2 - mw);
      float fs = 1.f / (f0 + f1 + f2);
      float sw0 = f0 * fs, sw1 = f1 * fs, sw2 = f2 * fs;

      const int l  = l0 + tid;
      const int lm = (l - 1) & (L_MEM - 1);
      const int lp = (l + 1) & (L_MEM - 1);
      const int base = b * L_MEM;
      float aR = gR * invSR, bRc = 1.f - gR;
      float wgm = aR * erR[base + lm] + bRc * wpR[base + lm];
      float wg0 = aR * erR[base + l]  + bRc * wpR[base + l];
      float wgp = aR * erR[base + lp] + bRc * wpR[base + lp];
      float wR = __powf(sr0 * wgm + sr1 * wg0 + sr2 * wgp, gaR);
      wbR[base + l] = wR;
      float aW = gW * invSW, bWc = 1.f - gW;
      float vgm = aW * erW[base + lm] + bWc * wpW[base + lm];
      float vg0 = aW * erW[base + l]  + bWc * wpW[base + l];
      float vgp = aW * erW[base + lp] + bWc * wpW[base + lp];
      float wW = __powf(sw0 * vgm + sw1 * vg0 + sw2 * vgp, gaW);
      wbW[base + l] = wW;
      float p1 = waveSum(wR), p2 = waveSum(wW);
      if (lane == 0) { atomicAdd(&Sbuf[32 + b], p1); atomicAdd(&Sbuf[48 + b], p2); }
      if (chunk == 0 && tid < W_DIM) Rbuf[b * W_DIM + tid] = 0.f;   // zero R
    }
    __threadfence();
    grid.sync();   // sync b

    // ---------------- phase 4: read vector + memory update ----------------
    {
      const float invPR = 1.f / Sbuf[32 + b];
      const float invPW = 1.f / Sbuf[48 + b];
      if (tid < W_DIM) {
        rpart[tid] = 0.f;
        elds[tid] = sigmoidf(praw[b * CO + 204 + tid]);
        alds[tid] = praw[b * CO + 268 + tid];
      }
      __syncthreads();
      const int l = l0 + wave * 64 + lane;
      const int base = b * L_MEM;
      float rwl = wbR[base + l] * invPR;
      float wwl = wbW[base + l] * invPW;
      wpR[base + l] = rwl;   // becomes w_prev for next step
      wpW[base + l] = wwl;
      float* mp = mT + l;
#pragma unroll 4
      for (int w = 0; w < W_DIM; ++w) {
        float v = mp[(size_t)w * L_MEM];
        float p = waveSum(v * rwl);
        if (lane == 0) atomicAdd(&rpart[w], p);
        float t1 = wwl * elds[w];
        float nv = fmaf(v, -t1, v);        // v*(1 - ww*e)
        nv = fmaf(wwl, alds[w], nv);       // + ww*a
        mp[(size_t)w * L_MEM] = nv;
      }
      __syncthreads();
      if (tid < W_DIM) atomicAdd(&Rbuf[b * W_DIM + tid], rpart[tid]);
      if (chunk == 0 && tid == 0) { Sbuf[b] = 0.f; Sbuf[16 + b] = 0.f; }  // zero S
    }
    __threadfence();
    grid.sync();   // sync c
  }
}

extern "C" void kernel_launch(void* const* d_in, const int* in_sizes, int n_in,
                              void* d_out, int out_size, void* d_ws, size_t ws_size,
                              hipStream_t stream) {
  const float* inp = (const float*)d_in[0];
  const float* Wc  = (const float*)d_in[1];
  const float* bcv = (const float*)d_in[2];
  float* dout = (float*)d_out;
  float* ws = (float*)d_ws;

  size_t off = 0;
  float* memT = ws + off; off += (size_t)BATCH * W_DIM * L_MEM;  // 16 MB
  float* erR  = ws + off; off += (size_t)BATCH * L_MEM;
  float* erW  = ws + off; off += (size_t)BATCH * L_MEM;
  float* wbR  = ws + off; off += (size_t)BATCH * L_MEM;
  float* wbW  = ws + off; off += (size_t)BATCH * L_MEM;
  float* wpR  = ws + off; off += (size_t)BATCH * L_MEM;
  float* wpW  = ws + off; off += (size_t)BATCH * L_MEM;
  float* outbuf = ws + off; off += 2 * BATCH * OUT_DIM;
  float* Rbuf   = ws + off; off += BATCH * W_DIM;
  float* Sbuf   = ws + off; off += 64;
  float* praw   = ws + off; off += BATCH * CO;

  void* args[] = { (void*)&inp, (void*)&Wc, (void*)&bcv, (void*)&dout,
                   (void*)&memT, (void*)&erR, (void*)&erW, (void*)&wbR, (void*)&wbW,
                   (void*)&wpR, (void*)&wpW, (void*)&outbuf, (void*)&Rbuf,
                   (void*)&Sbuf, (void*)&praw };
  hipLaunchCooperativeKernel((void*)ntm_kernel, dim3(NBLK), dim3(NTHR),
                             args, 0, stream);
}